// Round 12
// baseline (5627.909 us; speedup 1.0000x reference)
//
#include <hip/hip_runtime.h>
#include <math.h>

#define HD 1024
#define NBATCH 256
#define VOC 32000
#define TSTEPS 20
#define OUT_ROW 640000LL   // 20*32000, row stride (floats) between b rows in d_out
#define BH ((size_t)NBATCH * HD)
#define NCHUNK 500         // 32000 / 64
#define THR 0.125f         // candidate window for exact-argmax rescue

typedef _Float16 f16;
typedef __attribute__((ext_vector_type(4))) _Float16 f16x4;
typedef __attribute__((ext_vector_type(8))) _Float16 f16x8;
typedef __attribute__((ext_vector_type(4))) float f32x4;

#define GLOBAL_AS __attribute__((address_space(1)))
#define LDS_AS    __attribute__((address_space(3)))

static __device__ __forceinline__ float sigmoidf_(float v) {
  return 1.0f / (1.0f + expf(-v));
}

// ================= conversion kernels =================

__global__ void f32_to_f16_k(const float* __restrict__ in, f16* __restrict__ out, long n8) {
  long i = (long)blockIdx.x * 256 + threadIdx.x;
  long stride = (long)gridDim.x * 256;
  for (; i < n8; i += stride) {
    float4 a = *((const float4*)in + i * 2);
    float4 b = *((const float4*)in + i * 2 + 1);
    f16x8 o;
    o[0] = (f16)a.x; o[1] = (f16)a.y; o[2] = (f16)a.z; o[3] = (f16)a.w;
    o[4] = (f16)b.x; o[5] = (f16)b.y; o[6] = (f16)b.z; o[7] = (f16)b.w;
    *((f16x8*)out + i) = o;
  }
}

__global__ void split_f32_k(const float* __restrict__ in, f16* __restrict__ hi,
                            f16* __restrict__ lo, long n8) {
  long i = (long)blockIdx.x * 256 + threadIdx.x;
  long stride = (long)gridDim.x * 256;
  for (; i < n8; i += stride) {
    float4 a = *((const float4*)in + i * 2);
    float4 b = *((const float4*)in + i * 2 + 1);
    float v[8] = {a.x, a.y, a.z, a.w, b.x, b.y, b.z, b.w};
    f16x8 h8, l8;
    #pragma unroll
    for (int j = 0; j < 8; ++j) {
      f16 h = (f16)v[j];
      h8[j] = h;
      l8[j] = (f16)(v[j] - (float)h);
    }
    *((f16x8*)hi + i) = h8;
    *((f16x8*)lo + i) = l8;
  }
}

// ================= GRU GEMM v7: logits-skeleton =================
// gg2[z][b][0:3072] = x @ w_ih^T (K-half z) ; gg2[z][b][3072:6144] = h @ w_hh^T
// tile 64(M) x 64(N), 4 waves (2x2 of 32x32), K-split x2 (z), BK=32.
// B: pre-split f16 planes via global_load_lds into padded kg-rows (dbuf).
// A: register double-buffer prefetch from h-split planes (embmode: emb+relu+split).
// MFMA order/K-order identical to r8 -> gg2 bit-identical.
__global__ __launch_bounds__(256)
void gemm_gru_mfma7_k(const f16* __restrict__ a0_hi, const f16* __restrict__ a0_lo,
                      const f16* __restrict__ a1_hi, const f16* __restrict__ a1_lo,
                      const float* __restrict__ emb, const int* __restrict__ tok, int use_emb,
                      const f16* __restrict__ wih_hi, const f16* __restrict__ wih_lo,
                      const f16* __restrict__ whh_hi, const f16* __restrict__ whh_lo,
                      float* __restrict__ gg2) {
  __shared__ f16 lbh[2][2112];   // [buf][4 kg-rows x 528 f16] padded (1056 B rows)
  __shared__ f16 lbl[2][2112];

  const int tid = threadIdx.x;
  const int lane = tid & 63;
  const int wave = tid >> 6;
  const int wm = wave >> 1, wn = wave & 1;
  const int l15 = lane & 15, l4 = lane >> 4;
  const int n0g = blockIdx.x * 64;   // 0..6080
  const int m0 = blockIdx.y * 64;    // 0..192
  const int kb = blockIdx.z * 512;   // K-half

  const f16 *ahi, *alo, *whi, *wlo; int nc;
  if (n0g < 3072) { ahi = a0_hi; alo = a0_lo; whi = wih_hi; wlo = wih_lo; nc = n0g; }
  else            { ahi = a1_hi; alo = a1_lo; whi = whh_hi; wlo = whh_lo; nc = n0g - 3072; }
  const bool embmode = use_emb && (n0g < 3072);

  f32x4 acc[2][2];
  #pragma unroll
  for (int mi = 0; mi < 2; ++mi)
    #pragma unroll
    for (int ni = 0; ni < 2; ++ni) acc[mi][ni] = (f32x4){0.f, 0.f, 0.f, 0.f};

  // A per-lane bases
  const int arow0 = m0 + wm * 32 + l15;
  const f16* ap_h = ahi + (size_t)arow0 * HD + kb + l4 * 8;
  const f16* ap_l = alo + (size_t)arow0 * HD + kb + l4 * 8;
  const float* ep0 = embmode ? (emb + (size_t)tok[arow0] * HD + kb + l4 * 8) : (const float*)0;
  const float* ep1 = embmode ? (emb + (size_t)tok[arow0 + 16] * HD + kb + l4 * 8) : (const float*)0;

  // B staging: wave stages kg-row = wave of both planes (64-lane row gather, DMA)
  #define STAGE(kt, buf) { \
    const size_t so = (size_t)(nc + lane) * HD + kb + (kt) * 32 + wave * 8; \
    __builtin_amdgcn_global_load_lds((const GLOBAL_AS void*)(whi + so), \
        (LDS_AS void*)(lbh[buf] + wave * 528), 16, 0, 0); \
    __builtin_amdgcn_global_load_lds((const GLOBAL_AS void*)(wlo + so), \
        (LDS_AS void*)(lbl[buf] + wave * 528), 16, 0, 0); }

  // A register load for K-tile kt
  #define LOADA(kt, dh, dl) { \
    if (embmode) { \
      _Pragma("unroll") \
      for (int mi = 0; mi < 2; ++mi) { \
        const float* ep = mi ? ep1 : ep0; \
        float4 e0 = *(const float4*)(ep + (kt) * 32); \
        float4 e1 = *(const float4*)(ep + (kt) * 32 + 4); \
        float av[8] = {fmaxf(e0.x,0.f), fmaxf(e0.y,0.f), fmaxf(e0.z,0.f), fmaxf(e0.w,0.f), \
                       fmaxf(e1.x,0.f), fmaxf(e1.y,0.f), fmaxf(e1.z,0.f), fmaxf(e1.w,0.f)}; \
        _Pragma("unroll") \
        for (int j = 0; j < 8; ++j) { \
          f16 h = (f16)av[j]; dh[mi][j] = h; dl[mi][j] = (f16)(av[j] - (float)h); \
        } \
      } \
    } else { \
      dh[0] = *(const f16x8*)(ap_h + (kt) * 32); \
      dh[1] = *(const f16x8*)(ap_h + (size_t)16 * HD + (kt) * 32); \
      dl[0] = *(const f16x8*)(ap_l + (kt) * 32); \
      dl[1] = *(const f16x8*)(ap_l + (size_t)16 * HD + (kt) * 32); \
    } }

  f16x8 ach[2], acl[2], anh[2], anl[2];
  STAGE(0, 0);
  LOADA(0, ach, acl);
  __syncthreads();

  for (int kt = 0; kt < 16; ++kt) {
    const int cur = kt & 1;
    f16x8 fbh[2], fbl[2];
    #pragma unroll
    for (int ni = 0; ni < 2; ++ni) {
      const int off = l4 * 528 + (wn * 32 + ni * 16 + l15) * 8;
      fbh[ni] = *(const f16x8*)(lbh[cur] + off);
      fbl[ni] = *(const f16x8*)(lbl[cur] + off);
    }
    if (kt < 15) {
      STAGE(kt + 1, cur ^ 1);
      LOADA(kt + 1, anh, anl);
    }
    #pragma unroll
    for (int mi = 0; mi < 2; ++mi)
      #pragma unroll
      for (int ni = 0; ni < 2; ++ni) {
        acc[mi][ni] = __builtin_amdgcn_mfma_f32_16x16x32_f16(ach[mi], fbh[ni], acc[mi][ni], 0, 0, 0);
        acc[mi][ni] = __builtin_amdgcn_mfma_f32_16x16x32_f16(ach[mi], fbl[ni], acc[mi][ni], 0, 0, 0);
        acc[mi][ni] = __builtin_amdgcn_mfma_f32_16x16x32_f16(acl[mi], fbh[ni], acc[mi][ni], 0, 0, 0);
      }
    __syncthreads();
    if (kt < 15) {
      #pragma unroll
      for (int mi = 0; mi < 2; ++mi) { ach[mi] = anh[mi]; acl[mi] = anl[mi]; }
    }
  }
  #undef STAGE
  #undef LOADA

  float* outp = gg2 + (size_t)blockIdx.z * NBATCH * 6144;
  #pragma unroll
  for (int mi = 0; mi < 2; ++mi)
    #pragma unroll
    for (int ni = 0; ni < 2; ++ni) {
      const int col = n0g + wn * 32 + ni * 16 + l15;
      #pragma unroll
      for (int r = 0; r < 4; ++r) {
        const int row = m0 + wm * 32 + mi * 16 + l4 * 4 + r;
        outp[(size_t)row * 6144 + col] = acc[mi][ni][r];
      }
    }
}

// ================= GRU gates (validated r7/r8/r11) =================
static __device__ __forceinline__ float4 add4_(float4 a, float4 b) {
  float4 r; r.x = a.x + b.x; r.y = a.y + b.y; r.z = a.z + b.z; r.w = a.w + b.w; return r;
}
__global__ void gru_gates_split2_k(const float* __restrict__ gg2,
                                   const float* __restrict__ b_ih, const float* __restrict__ b_hh,
                                   const f16* __restrict__ hold_hi, const f16* __restrict__ hold_lo,
                                   f16* __restrict__ hnew_hi, f16* __restrict__ hnew_lo) {
  int idx = blockIdx.x * 256 + threadIdx.x;   // 65536
  int b = idx >> 8;
  int k4 = (idx & 255) << 2;
  const float* g0 = gg2 + (size_t)b * 6144;
  const float* g1 = gg2 + (size_t)NBATCH * 6144 + (size_t)b * 6144;
  #define LD2(off) add4_(*(const float4*)(g0 + (off) + k4), *(const float4*)(g1 + (off) + k4))
  float4 gir = LD2(0);
  float4 giz = LD2(1024);
  float4 gin = LD2(2048);
  float4 ghr = LD2(3072);
  float4 ghz = LD2(4096);
  float4 ghn = LD2(5120);
  #undef LD2
  float4 bir = *(const float4*)(b_ih + k4);
  float4 biz = *(const float4*)(b_ih + 1024 + k4);
  float4 bin = *(const float4*)(b_ih + 2048 + k4);
  float4 bhr = *(const float4*)(b_hh + k4);
  float4 bhz = *(const float4*)(b_hh + 1024 + k4);
  float4 bhn = *(const float4*)(b_hh + 2048 + k4);
  f16x4 hh = *(const f16x4*)(hold_hi + (size_t)b * HD + k4);
  f16x4 hl = *(const f16x4*)(hold_lo + (size_t)b * HD + k4);
  float hov[4];
  #pragma unroll
  for (int j = 0; j < 4; ++j) hov[j] = (float)hh[j] + (float)hl[j];
  float4 ho; ho.x = hov[0]; ho.y = hov[1]; ho.z = hov[2]; ho.w = hov[3];
  float4 o;
  #define GATE(c) { \
    float rr = sigmoidf_(gir.c + bir.c + ghr.c + bhr.c); \
    float zz = sigmoidf_(giz.c + biz.c + ghz.c + bhz.c); \
    float nn = tanhf(gin.c + bin.c + rr * (ghn.c + bhn.c)); \
    o.c = (1.0f - zz) * nn + zz * ho.c; }
  GATE(x) GATE(y) GATE(z) GATE(w)
  #undef GATE
  float vv[4] = {o.x, o.y, o.z, o.w};
  f16x4 h4, l4;
  #pragma unroll
  for (int j = 0; j < 4; ++j) {
    f16 h = (f16)vv[j];
    h4[j] = h;
    l4[j] = (f16)(vv[j] - (float)h);
  }
  *(f16x4*)(hnew_hi + (size_t)b * HD + k4) = h4;
  *(f16x4*)(hnew_lo + (size_t)b * HD + k4) = l4;
}

// ================= logits GEMM v3 (r11 verbatim, dst = ws scratch stride VOC) ======
__global__ __launch_bounds__(256)
void gemm_logits3_k(const f16* __restrict__ xf, const f16* __restrict__ wf,
                    const float* __restrict__ bias, float* __restrict__ scr,
                    float* __restrict__ pmax, float* __restrict__ psum) {
  __shared__ f16 lb[2][2112];                 // 2 x 4224 B
  const int tid = threadIdx.x;
  const int lane = tid & 63;
  const int wave = tid >> 6;
  const int l15 = lane & 15, l4 = lane >> 4;
  const int chunk = blockIdx.x;
  const int n0 = chunk * 64;

  f32x4 acc[4][4];
  #pragma unroll
  for (int mi = 0; mi < 4; ++mi)
    #pragma unroll
    for (int ni = 0; ni < 4; ++ni) acc[mi][ni] = (f32x4){0.f, 0.f, 0.f, 0.f};

  f16x8 a_cur[4], a_nxt[4];

  #define STAGE(k0, buf) { \
    const f16* src = wf + (size_t)(n0 + lane) * 1024 + (k0) + wave * 8; \
    __builtin_amdgcn_global_load_lds((const GLOBAL_AS void*)src, \
        (LDS_AS void*)(lb[buf] + wave * 528), 16, 0, 0); }
  #define LOADA(k0, dst) { \
    _Pragma("unroll") \
    for (int mi = 0; mi < 4; ++mi) { \
      int row = wave * 64 + mi * 16 + l15; \
      dst[mi] = *(const f16x8*)(xf + (size_t)row * 1024 + (k0) + l4 * 8); \
    } }

  STAGE(0, 0);
  LOADA(0, a_cur);
  __syncthreads();

  for (int kt = 0; kt < 32; ++kt) {
    const int cur = kt & 1;
    f16x8 b[4];
    #pragma unroll
    for (int ni = 0; ni < 4; ++ni)
      b[ni] = *(const f16x8*)(lb[cur] + (size_t)l4 * 528 + (size_t)(ni * 16 + l15) * 8);
    if (kt < 31) {
      STAGE((kt + 1) * 32, cur ^ 1);
      LOADA((kt + 1) * 32, a_nxt);
    }
    #pragma unroll
    for (int mi = 0; mi < 4; ++mi)
      #pragma unroll
      for (int ni = 0; ni < 4; ++ni)
        acc[mi][ni] = __builtin_amdgcn_mfma_f32_16x16x32_f16(a_cur[mi], b[ni], acc[mi][ni], 0, 0, 0);
    __syncthreads();
    #pragma unroll
    for (int mi = 0; mi < 4; ++mi) a_cur[mi] = a_nxt[mi];
  }
  #undef STAGE
  #undef LOADA

  float bv[4];
  #pragma unroll
  for (int ni = 0; ni < 4; ++ni) bv[ni] = bias[n0 + ni * 16 + l15];

  #pragma unroll
  for (int mi = 0; mi < 4; ++mi) {
    #pragma unroll
    for (int r = 0; r < 4; ++r) {
      const int row = wave * 64 + mi * 16 + l4 * 4 + r;
      float v[4];
      #pragma unroll
      for (int ni = 0; ni < 4; ++ni) {
        v[ni] = acc[mi][ni][r] + bv[ni];
        scr[(size_t)row * VOC + n0 + ni * 16 + l15] = v[ni];
      }
      float m = fmaxf(fmaxf(v[0], v[1]), fmaxf(v[2], v[3]));
      #pragma unroll
      for (int d = 1; d < 16; d <<= 1) m = fmaxf(m, __shfl_xor(m, d, 64));
      float s = __expf(v[0] - m) + __expf(v[1] - m) + __expf(v[2] - m) + __expf(v[3] - m);
      #pragma unroll
      for (int d = 1; d < 16; d <<= 1) s += __shfl_xor(s, d, 64);
      if (l15 == 0) {
        pmax[(size_t)row * NCHUNK + chunk] = m;
        psum[(size_t)row * NCHUNK + chunk] = s;
      }
    }
  }
}

// ================= token_k (r11 verbatim) =================
__global__ __launch_bounds__(256)
void token_k(const float* __restrict__ pmax, const float* __restrict__ psum,
             const float* __restrict__ lg,          // raw logits scratch, stride VOC
             const f16* __restrict__ xhi, const f16* __restrict__ xlo,
             const float* __restrict__ w, const float* __restrict__ ob,
             float* __restrict__ lse_out, int* __restrict__ tok) {
  __shared__ float sm[256];
  __shared__ float ssum[256];
  __shared__ double sd[256];
  __shared__ int sfl[16];
  __shared__ int scand[32];
  __shared__ int sflc, scnt;
  const int b = blockIdx.x;
  const int tid = threadIdx.x;
  const float* PM = pmax + (size_t)b * NCHUNK;
  const float* PS = psum + (size_t)b * NCHUNK;

  float m = -3.4e38f, s = 0.0f;
  for (int c = tid; c < NCHUNK; c += 256) {
    float mc = PM[c], sc = PS[c];
    float M = fmaxf(m, mc);
    s = s * __expf(m - M) + sc * __expf(mc - M);
    m = M;
  }
  sm[tid] = m; ssum[tid] = s;
  if (tid == 0) { sflc = 0; scnt = 0; }
  __syncthreads();
  for (int off = 128; off; off >>= 1) {
    if (tid < off) {
      float m1 = sm[tid], m2 = sm[tid + off];
      float M = fmaxf(m1, m2);
      ssum[tid] = ssum[tid] * __expf(m1 - M) + ssum[tid + off] * __expf(m2 - M);
      sm[tid] = M;
    }
    __syncthreads();
  }
  const float gmax = sm[0];
  const float lse = gmax + logf(ssum[0]);
  if (tid == 0) lse_out[b] = lse;
  const float thr = gmax - THR;

  for (int c = tid; c < NCHUNK; c += 256) {
    if (PM[c] >= thr) {
      int p = atomicAdd(&sflc, 1);
      if (p < 16) sfl[p] = c;
    }
  }
  __syncthreads();
  const int nf = sflc < 16 ? sflc : 16;

  const int g = tid >> 6, li = tid & 63;
  for (int f0 = 0; f0 < nf; f0 += 4) {
    int f = f0 + g;
    if (f < nf) {
      float v = lg[(size_t)b * VOC + sfl[f] * 64 + li];
      if (v >= thr) {
        int p = atomicAdd(&scnt, 1);
        if (p < 32) scand[p] = sfl[f] * 64 + li;
      }
    }
  }
  __syncthreads();
  const int c = scnt < 32 ? scnt : 32;

  if (c == 1) {
    if (tid == 0) tok[b] = scand[0];
    return;
  }

  double best = -1.0e300; int bi = 0x7fffffff;
  for (int j = 0; j < c; ++j) {
    const int idx = scand[j];
    double p = 0.0;
    const f16* xh = xhi + (size_t)b * HD;
    const f16* xl = xlo + (size_t)b * HD;
    const float* wr = w + (size_t)idx * HD;
    for (int k = tid; k < HD; k += 256)
      p += ((double)xh[k] + (double)xl[k]) * (double)wr[k];
    sd[tid] = p;
    __syncthreads();
    for (int off = 128; off; off >>= 1) {
      if (tid < off) sd[tid] += sd[tid + off];
      __syncthreads();
    }
    if (tid == 0) sd[0] += (double)ob[idx];
    __syncthreads();
    double tot = sd[0];
    if (tot > best || (tot == best && idx < bi)) { best = tot; bi = idx; }
    __syncthreads();
  }
  if (tid == 0) tok[b] = bi;
}

// ================= per-step output write: out = scratch - lse (L3-hot read) =======
__global__ void write_out_k(const float* __restrict__ scr, const float* __restrict__ lse,
                            float* __restrict__ outp) {
  int idx = blockIdx.x * 256 + threadIdx.x;    // 2,048,000 = 8000 blocks
  int b = idx / 8000;
  int r = idx - b * 8000;
  float l = lse[b];
  float4 v = ((const float4*)(scr + (size_t)b * VOC))[r];
  v.x -= l; v.y -= l; v.z -= l; v.w -= l;
  ((float4*)(outp + (size_t)b * OUT_ROW))[r] = v;
}

// ================= final h output: out = hi + lo =================
__global__ void combine_h_k(const f16* __restrict__ hi, const f16* __restrict__ lo,
                            float* __restrict__ o, int n4) {
  int i = blockIdx.x * 256 + threadIdx.x;
  if (i >= n4) return;
  f16x4 h = ((const f16x4*)hi)[i];
  f16x4 l = ((const f16x4*)lo)[i];
  float4 v;
  v.x = (float)h[0] + (float)l[0];
  v.y = (float)h[1] + (float)l[1];
  v.z = (float)h[2] + (float)l[2];
  v.w = (float)h[3] + (float)l[3];
  ((float4*)o)[i] = v;
}

extern "C" void kernel_launch(void* const* d_in, const int* in_sizes, int n_in,
                              void* d_out, int out_size, void* d_ws, size_t ws_size,
                              hipStream_t stream) {
  (void)in_sizes; (void)n_in; (void)out_size;
  const float* enc_hidden = (const float*)d_in[1];   // [4,256,1024]
  const float* emb   = (const float*)d_in[2];        // [32000,1024]
  const float* w_ih  = (const float*)d_in[3];        // [4,3072,1024]
  const float* w_hh  = (const float*)d_in[4];        // [4,3072,1024]
  const float* b_ih  = (const float*)d_in[5];        // [4,3072]
  const float* b_hh  = (const float*)d_in[6];        // [4,3072]
  const float* out_w = (const float*)d_in[7];        // [32000,1024]
  const float* out_b = (const float*)d_in[8];        // [32000]
  float* out = (float*)d_out;

  size_t off = 0;
  char* base = (char*)d_ws;
  #define WSALLOC(bytes) ((void*)(base + off)); off += (((size_t)(bytes)) + 255) & ~(size_t)255
  float* gg2     = (float*) WSALLOC((size_t)2 * NBATCH * 6144 * 4);  // 12.6 MB
  f16*   hs_hi   = (f16*)   WSALLOC(2 * 4 * BH * 2);                 // 4.2 MB
  f16*   hs_lo   = (f16*)   WSALLOC(2 * 4 * BH * 2);                 // 4.2 MB
  int*   tok     = (int*)   WSALLOC(1024);
  float* pmax    = (float*) WSALLOC((size_t)NBATCH * NCHUNK * 4);    // 512 KB
  float* psum    = (float*) WSALLOC((size_t)NBATCH * NCHUNK * 4);    // 512 KB
  float* lse_all = (float*) WSALLOC((size_t)TSTEPS * NBATCH * 4);    // 20 KB
  f16*   wf16    = (f16*)   WSALLOC((size_t)VOC * HD * 2);           // 65.5 MB
  float* lgws    = (float*) WSALLOC((size_t)NBATCH * VOC * 4);       // 32.8 MB scratch
  f16*   wih_hi  = (f16*)   WSALLOC((size_t)4 * 3072 * HD * 2);      // 25.2 MB
  f16*   wih_lo  = (f16*)   WSALLOC((size_t)4 * 3072 * HD * 2);
  f16*   whh_hi  = (f16*)   WSALLOC((size_t)4 * 3072 * HD * 2);
  f16*   whh_lo  = (f16*)   WSALLOC((size_t)4 * 3072 * HD * 2);
  #undef WSALLOC
  if (off > ws_size) return;   // fail loudly rather than corrupt

  // one-time conversions (pre-split == in-kernel split bit-for-bit)
  f32_to_f16_k<<<2048, 256, 0, stream>>>(out_w, wf16, (long)VOC * HD / 8);
  split_f32_k<<<2048, 256, 0, stream>>>(w_ih, wih_hi, wih_lo, (long)4 * 3072 * HD / 8);
  split_f32_k<<<2048, 256, 0, stream>>>(w_hh, whh_hi, whh_lo, (long)4 * 3072 * HD / 8);
  split_f32_k<<<512, 256, 0, stream>>>(enc_hidden, hs_hi, hs_lo, (long)(4 * BH / 8));
  hipMemsetAsync(tok, 0, NBATCH * 4, stream);

  int p = 0;
  for (int t = 0; t < TSTEPS; ++t) {
    f16* hp_hi = hs_hi + (size_t)p * 4 * BH;
    f16* hp_lo = hs_lo + (size_t)p * 4 * BH;
    f16* hn_hi = hs_hi + (size_t)(1 - p) * 4 * BH;
    f16* hn_lo = hs_lo + (size_t)(1 - p) * 4 * BH;

    for (int l = 0; l < 4; ++l) {
      const f16* a0hi = (l == 0) ? hs_hi : hn_hi + (size_t)(l - 1) * BH;
      const f16* a0lo = (l == 0) ? hs_lo : hn_lo + (size_t)(l - 1) * BH;
      gemm_gru_mfma7_k<<<dim3(96, 4, 2), 256, 0, stream>>>(
          a0hi, a0lo, hp_hi + (size_t)l * BH, hp_lo + (size_t)l * BH,
          emb, tok, (l == 0) ? 1 : 0,
          wih_hi + (size_t)l * 3072 * HD, wih_lo + (size_t)l * 3072 * HD,
          whh_hi + (size_t)l * 3072 * HD, whh_lo + (size_t)l * 3072 * HD, gg2);
      gru_gates_split2_k<<<256, 256, 0, stream>>>(
          gg2, b_ih + l * 3072, b_hh + l * 3072,
          hp_hi + (size_t)l * BH, hp_lo + (size_t)l * BH,
          hn_hi + (size_t)l * BH, hn_lo + (size_t)l * BH);
    }

    gemm_logits3_k<<<NCHUNK, 256, 0, stream>>>(
        hn_hi + (size_t)3 * BH, wf16, out_b, lgws, pmax, psum);
    token_k<<<NBATCH, 256, 0, stream>>>(
        pmax, psum, lgws, hn_hi + (size_t)3 * BH, hn_lo + (size_t)3 * BH,
        out_w, out_b, lse_all + (size_t)t * NBATCH, tok);
    write_out_k<<<8000, 256, 0, stream>>>(
        lgws, lse_all + (size_t)t * NBATCH, out + (size_t)t * VOC);

    p ^= 1;
  }

  // after 20 steps the final h splits sit in parity 0
  combine_h_k<<<1024, 256, 0, stream>>>(hs_hi, hs_lo,
                                        out + (size_t)NBATCH * TSTEPS * VOC,
                                        (int)(4 * BH / 4));
}

// Round 13
// 3984.915 us; speedup vs baseline: 1.4123x; 1.4123x over previous
//
#include <hip/hip_runtime.h>
#include <math.h>

#define HD 1024
#define NBATCH 256
#define VOC 32000
#define TSTEPS 20
#define OUT_ROW 640000LL   // 20*32000, row stride (floats) between b rows in d_out
#define BH ((size_t)NBATCH * HD)
#define NCHUNK 500         // 32000 / 64
#define THR 0.125f         // candidate window (~100x the f16-GEMM logit error bound)

typedef _Float16 f16;
typedef __attribute__((ext_vector_type(4))) _Float16 f16x4;
typedef __attribute__((ext_vector_type(8))) _Float16 f16x8;
typedef __attribute__((ext_vector_type(4))) float f32x4;

#define GLOBAL_AS __attribute__((address_space(1)))
#define LDS_AS    __attribute__((address_space(3)))

static __device__ __forceinline__ float sigmoidf_(float v) {
  return 1.0f / (1.0f + expf(-v));
}

// ================= conversion kernels =================

__global__ void f32_to_f16_k(const float* __restrict__ in, f16* __restrict__ out, long n8) {
  long i = (long)blockIdx.x * 256 + threadIdx.x;
  long stride = (long)gridDim.x * 256;
  for (; i < n8; i += stride) {
    float4 a = *((const float4*)in + i * 2);
    float4 b = *((const float4*)in + i * 2 + 1);
    f16x8 o;
    o[0] = (f16)a.x; o[1] = (f16)a.y; o[2] = (f16)a.z; o[3] = (f16)a.w;
    o[4] = (f16)b.x; o[5] = (f16)b.y; o[6] = (f16)b.z; o[7] = (f16)b.w;
    *((f16x8*)out + i) = o;
  }
}

__global__ void split_f32_k(const float* __restrict__ in, f16* __restrict__ hi,
                            f16* __restrict__ lo, long n8) {
  long i = (long)blockIdx.x * 256 + threadIdx.x;
  long stride = (long)gridDim.x * 256;
  for (; i < n8; i += stride) {
    float4 a = *((const float4*)in + i * 2);
    float4 b = *((const float4*)in + i * 2 + 1);
    float v[8] = {a.x, a.y, a.z, a.w, b.x, b.y, b.z, b.w};
    f16x8 h8, l8;
    #pragma unroll
    for (int j = 0; j < 8; ++j) {
      f16 h = (f16)v[j];
      h8[j] = h;
      l8[j] = (f16)(v[j] - (float)h);
    }
    *((f16x8*)hi + i) = h8;
    *((f16x8*)lo + i) = l8;
  }
}

// ================= GRU GEMM v4 (validated r7/r8): dbuf LDS, embed-fused layer 0 ======
__global__ __launch_bounds__(256)
void gemm_gru_mfma4_k(const f16* __restrict__ a0_hi, const f16* __restrict__ a0_lo,
                      const f16* __restrict__ a1_hi, const f16* __restrict__ a1_lo,
                      const float* __restrict__ emb, const int* __restrict__ tok, int use_emb,
                      const float* __restrict__ w_ih, const float* __restrict__ w_hh,
                      float* __restrict__ gg2) {
  __shared__ f16x8 atoms[2][1088];   // 2 x 17408 B

  const int tid = threadIdx.x;
  const int lane = tid & 63;
  const int wave = tid >> 6;
  const int wm = wave >> 1, wn = wave & 1;
  const int l15 = lane & 15, l4 = lane >> 4;
  const int n0g = blockIdx.x * 64;   // 0..6080
  const int m0 = blockIdx.y * 64;    // 0..192
  const int kb = blockIdx.z * 512;   // K-half

  const f16 *ahi, *alo; const float* W; int nc;
  if (n0g < 3072) { ahi = a0_hi; alo = a0_lo; W = w_ih; nc = n0g; }
  else            { ahi = a1_hi; alo = a1_lo; W = w_hh; nc = n0g - 3072; }
  const bool embmode = use_emb && (n0g < 3072);

  f32x4 acc[2][2];
  #pragma unroll
  for (int mi = 0; mi < 2; ++mi)
    #pragma unroll
    for (int ni = 0; ni < 2; ++ni) acc[mi][ni] = (f32x4){0.f, 0.f, 0.f, 0.f};

  const int sr = tid >> 2, skg = tid & 3;
  const int satom = skg * 68 + sr;
  const float* wgp = W + (size_t)(nc + sr) * HD + kb + skg * 8;
  const f16* agh = ahi + (size_t)(m0 + sr) * HD + kb + skg * 8;
  const f16* agl = alo + (size_t)(m0 + sr) * HD + kb + skg * 8;
  const float* egp = embmode ? (emb + (size_t)tok[m0 + sr] * HD + kb + skg * 8) : wgp;

  #define LOADREGS(k0, rah, ral, wbh, wbl) { \
    if (embmode) { \
      float4 e0 = *(const float4*)(egp + (k0)); \
      float4 e1 = *(const float4*)(egp + (k0) + 4); \
      float av[8] = {fmaxf(e0.x,0.f), fmaxf(e0.y,0.f), fmaxf(e0.z,0.f), fmaxf(e0.w,0.f), \
                     fmaxf(e1.x,0.f), fmaxf(e1.y,0.f), fmaxf(e1.z,0.f), fmaxf(e1.w,0.f)}; \
      _Pragma("unroll") \
      for (int j = 0; j < 8; ++j) { \
        f16 h = (f16)av[j]; rah[j] = h; ral[j] = (f16)(av[j] - (float)h); \
      } \
    } else { \
      rah = *(const f16x8*)(agh + (k0)); \
      ral = *(const f16x8*)(agl + (k0)); \
    } \
    float4 w0 = *(const float4*)(wgp + (k0)); \
    float4 w1 = *(const float4*)(wgp + (k0) + 4); \
    float wv[8] = {w0.x, w0.y, w0.z, w0.w, w1.x, w1.y, w1.z, w1.w}; \
    _Pragma("unroll") \
    for (int j = 0; j < 8; ++j) { \
      f16 h = (f16)wv[j]; wbh[j] = h; wbl[j] = (f16)(wv[j] - (float)h); \
    } }

  {
    f16x8 rah, ral, wbh, wbl;
    LOADREGS(0, rah, ral, wbh, wbl);
    atoms[0][satom]       = rah;
    atoms[0][272 + satom] = ral;
    atoms[0][544 + satom] = wbh;
    atoms[0][816 + satom] = wbl;
  }
  __syncthreads();

  for (int kt = 0; kt < 16; ++kt) {
    const int cur = kt & 1;
    f16x8 nah, nal, nbh, nbl;
    if (kt < 15) { LOADREGS((kt + 1) * 32, nah, nal, nbh, nbl); }

    f16x8 fah[2], fal[2], fbh[2], fbl[2];
    #pragma unroll
    for (int mi = 0; mi < 2; ++mi) {
      int idx = l4 * 68 + wm * 32 + mi * 16 + l15;
      fah[mi] = atoms[cur][idx];
      fal[mi] = atoms[cur][272 + idx];
    }
    #pragma unroll
    for (int ni = 0; ni < 2; ++ni) {
      int idx = l4 * 68 + wn * 32 + ni * 16 + l15;
      fbh[ni] = atoms[cur][544 + idx];
      fbl[ni] = atoms[cur][816 + idx];
    }
    #pragma unroll
    for (int mi = 0; mi < 2; ++mi)
      #pragma unroll
      for (int ni = 0; ni < 2; ++ni) {
        acc[mi][ni] = __builtin_amdgcn_mfma_f32_16x16x32_f16(fah[mi], fbh[ni], acc[mi][ni], 0, 0, 0);
        acc[mi][ni] = __builtin_amdgcn_mfma_f32_16x16x32_f16(fah[mi], fbl[ni], acc[mi][ni], 0, 0, 0);
        acc[mi][ni] = __builtin_amdgcn_mfma_f32_16x16x32_f16(fal[mi], fbh[ni], acc[mi][ni], 0, 0, 0);
      }

    if (kt < 15) {
      atoms[cur ^ 1][satom]       = nah;
      atoms[cur ^ 1][272 + satom] = nal;
      atoms[cur ^ 1][544 + satom] = nbh;
      atoms[cur ^ 1][816 + satom] = nbl;
    }
    __syncthreads();
  }
  #undef LOADREGS

  float* outp = gg2 + (size_t)blockIdx.z * NBATCH * 6144;
  #pragma unroll
  for (int mi = 0; mi < 2; ++mi)
    #pragma unroll
    for (int ni = 0; ni < 2; ++ni) {
      const int col = n0g + wn * 32 + ni * 16 + l15;
      #pragma unroll
      for (int r = 0; r < 4; ++r) {
        const int row = m0 + wm * 32 + mi * 16 + l4 * 4 + r;
        outp[(size_t)row * 6144 + col] = acc[mi][ni][r];
      }
    }
}

// ================= GRU gates (validated r7/r8) =================
static __device__ __forceinline__ float4 add4_(float4 a, float4 b) {
  float4 r; r.x = a.x + b.x; r.y = a.y + b.y; r.z = a.z + b.z; r.w = a.w + b.w; return r;
}
__global__ void gru_gates_split2_k(const float* __restrict__ gg2,
                                   const float* __restrict__ b_ih, const float* __restrict__ b_hh,
                                   const f16* __restrict__ hold_hi, const f16* __restrict__ hold_lo,
                                   f16* __restrict__ hnew_hi, f16* __restrict__ hnew_lo) {
  int idx = blockIdx.x * 256 + threadIdx.x;   // 65536
  int b = idx >> 8;
  int k4 = (idx & 255) << 2;
  const float* g0 = gg2 + (size_t)b * 6144;
  const float* g1 = gg2 + (size_t)NBATCH * 6144 + (size_t)b * 6144;
  #define LD2(off) add4_(*(const float4*)(g0 + (off) + k4), *(const float4*)(g1 + (off) + k4))
  float4 gir = LD2(0);
  float4 giz = LD2(1024);
  float4 gin = LD2(2048);
  float4 ghr = LD2(3072);
  float4 ghz = LD2(4096);
  float4 ghn = LD2(5120);
  #undef LD2
  float4 bir = *(const float4*)(b_ih + k4);
  float4 biz = *(const float4*)(b_ih + 1024 + k4);
  float4 bin = *(const float4*)(b_ih + 2048 + k4);
  float4 bhr = *(const float4*)(b_hh + k4);
  float4 bhz = *(const float4*)(b_hh + 1024 + k4);
  float4 bhn = *(const float4*)(b_hh + 2048 + k4);
  f16x4 hh = *(const f16x4*)(hold_hi + (size_t)b * HD + k4);
  f16x4 hl = *(const f16x4*)(hold_lo + (size_t)b * HD + k4);
  float hov[4];
  #pragma unroll
  for (int j = 0; j < 4; ++j) hov[j] = (float)hh[j] + (float)hl[j];
  float4 ho; ho.x = hov[0]; ho.y = hov[1]; ho.z = hov[2]; ho.w = hov[3];
  float4 o;
  #define GATE(c) { \
    float rr = sigmoidf_(gir.c + bir.c + ghr.c + bhr.c); \
    float zz = sigmoidf_(giz.c + biz.c + ghz.c + bhz.c); \
    float nn = tanhf(gin.c + bin.c + rr * (ghn.c + bhn.c)); \
    o.c = (1.0f - zz) * nn + zz * ho.c; }
  GATE(x) GATE(y) GATE(z) GATE(w)
  #undef GATE
  float vv[4] = {o.x, o.y, o.z, o.w};
  f16x4 h4, l4;
  #pragma unroll
  for (int j = 0; j < 4; ++j) {
    f16 h = (f16)vv[j];
    h4[j] = h;
    l4[j] = (f16)(vv[j] - (float)h);
  }
  *(f16x4*)(hnew_hi + (size_t)b * HD + k4) = h4;
  *(f16x4*)(hnew_lo + (size_t)b * HD + k4) = l4;
}

// ================= logits GEMM v3 (validated r8): BM=256 x BN=64 + max/sumexp epilogue
__global__ __launch_bounds__(256)
void gemm_logits3_k(const f16* __restrict__ xf, const f16* __restrict__ wf,
                    const float* __restrict__ bias, float* __restrict__ out,
                    float* __restrict__ pmax, float* __restrict__ psum) {
  __shared__ f16 lb[2][2112];                 // 2 x 4224 B
  const int tid = threadIdx.x;
  const int lane = tid & 63;
  const int wave = tid >> 6;
  const int l15 = lane & 15, l4 = lane >> 4;
  const int chunk = blockIdx.x;
  const int n0 = chunk * 64;

  f32x4 acc[4][4];
  #pragma unroll
  for (int mi = 0; mi < 4; ++mi)
    #pragma unroll
    for (int ni = 0; ni < 4; ++ni) acc[mi][ni] = (f32x4){0.f, 0.f, 0.f, 0.f};

  f16x8 a_cur[4], a_nxt[4];

  #define STAGE(k0, buf) { \
    const f16* src = wf + (size_t)(n0 + lane) * 1024 + (k0) + wave * 8; \
    __builtin_amdgcn_global_load_lds((const GLOBAL_AS void*)src, \
        (LDS_AS void*)(lb[buf] + wave * 528), 16, 0, 0); }
  #define LOADA(k0, dst) { \
    _Pragma("unroll") \
    for (int mi = 0; mi < 4; ++mi) { \
      int row = wave * 64 + mi * 16 + l15; \
      dst[mi] = *(const f16x8*)(xf + (size_t)row * 1024 + (k0) + l4 * 8); \
    } }

  STAGE(0, 0);
  LOADA(0, a_cur);
  __syncthreads();

  for (int kt = 0; kt < 32; ++kt) {
    const int cur = kt & 1;
    f16x8 b[4];
    #pragma unroll
    for (int ni = 0; ni < 4; ++ni)
      b[ni] = *(const f16x8*)(lb[cur] + (size_t)l4 * 528 + (size_t)(ni * 16 + l15) * 8);
    if (kt < 31) {
      STAGE((kt + 1) * 32, cur ^ 1);
      LOADA((kt + 1) * 32, a_nxt);
    }
    #pragma unroll
    for (int mi = 0; mi < 4; ++mi)
      #pragma unroll
      for (int ni = 0; ni < 4; ++ni)
        acc[mi][ni] = __builtin_amdgcn_mfma_f32_16x16x32_f16(a_cur[mi], b[ni], acc[mi][ni], 0, 0, 0);
    __syncthreads();
    #pragma unroll
    for (int mi = 0; mi < 4; ++mi) a_cur[mi] = a_nxt[mi];
  }
  #undef STAGE
  #undef LOADA

  float bv[4];
  #pragma unroll
  for (int ni = 0; ni < 4; ++ni) bv[ni] = bias[n0 + ni * 16 + l15];

  #pragma unroll
  for (int mi = 0; mi < 4; ++mi) {
    #pragma unroll
    for (int r = 0; r < 4; ++r) {
      const int row = wave * 64 + mi * 16 + l4 * 4 + r;
      float v[4];
      #pragma unroll
      for (int ni = 0; ni < 4; ++ni) {
        v[ni] = acc[mi][ni][r] + bv[ni];
        out[(size_t)row * OUT_ROW + n0 + ni * 16 + l15] = v[ni];
      }
      float m = fmaxf(fmaxf(v[0], v[1]), fmaxf(v[2], v[3]));
      #pragma unroll
      for (int d = 1; d < 16; d <<= 1) m = fmaxf(m, __shfl_xor(m, d, 64));
      float s = __expf(v[0] - m) + __expf(v[1] - m) + __expf(v[2] - m) + __expf(v[3] - m);
      #pragma unroll
      for (int d = 1; d < 16; d <<= 1) s += __shfl_xor(s, d, 64);
      if (l15 == 0) {
        pmax[(size_t)row * NCHUNK + chunk] = m;
        psum[(size_t)row * NCHUNK + chunk] = s;
      }
    }
  }
}

// ================= token_k (validated r8) =================
__global__ __launch_bounds__(256)
void token_k(const float* __restrict__ pmax, const float* __restrict__ psum,
             const float* __restrict__ lg,          // raw logits, row stride OUT_ROW
             const f16* __restrict__ xhi, const f16* __restrict__ xlo,
             const float* __restrict__ w, const float* __restrict__ ob,
             float* __restrict__ lse_out, int* __restrict__ tok) {
  __shared__ float sm[256];
  __shared__ float ssum[256];
  __shared__ double sd[256];
  __shared__ int sfl[16];
  __shared__ int scand[32];
  __shared__ int sflc, scnt;
  const int b = blockIdx.x;
  const int tid = threadIdx.x;
  const float* PM = pmax + (size_t)b * NCHUNK;
  const float* PS = psum + (size_t)b * NCHUNK;

  float m = -3.4e38f, s = 0.0f;
  for (int c = tid; c < NCHUNK; c += 256) {
    float mc = PM[c], sc = PS[c];
    float M = fmaxf(m, mc);
    s = s * __expf(m - M) + sc * __expf(mc - M);
    m = M;
  }
  sm[tid] = m; ssum[tid] = s;
  if (tid == 0) { sflc = 0; scnt = 0; }
  __syncthreads();
  for (int off = 128; off; off >>= 1) {
    if (tid < off) {
      float m1 = sm[tid], m2 = sm[tid + off];
      float M = fmaxf(m1, m2);
      ssum[tid] = ssum[tid] * __expf(m1 - M) + ssum[tid + off] * __expf(m2 - M);
      sm[tid] = M;
    }
    __syncthreads();
  }
  const float gmax = sm[0];
  const float lse = gmax + logf(ssum[0]);
  if (tid == 0) lse_out[b] = lse;
  const float thr = gmax - THR;

  for (int c = tid; c < NCHUNK; c += 256) {
    if (PM[c] >= thr) {
      int p = atomicAdd(&sflc, 1);
      if (p < 16) sfl[p] = c;
    }
  }
  __syncthreads();
  const int nf = sflc < 16 ? sflc : 16;

  const int g = tid >> 6, li = tid & 63;    // 4 chunk-groups of 64 lanes
  for (int f0 = 0; f0 < nf; f0 += 4) {
    int f = f0 + g;
    if (f < nf) {
      float v = lg[(size_t)b * OUT_ROW + sfl[f] * 64 + li];
      if (v >= thr) {
        int p = atomicAdd(&scnt, 1);
        if (p < 32) scand[p] = sfl[f] * 64 + li;
      }
    }
  }
  __syncthreads();
  const int c = scnt < 32 ? scnt : 32;

  if (c == 1) {
    if (tid == 0) tok[b] = scand[0];
    return;
  }

  double best = -1.0e300; int bi = 0x7fffffff;
  for (int j = 0; j < c; ++j) {
    const int idx = scand[j];
    double p = 0.0;
    const f16* xh = xhi + (size_t)b * HD;
    const f16* xl = xlo + (size_t)b * HD;
    const float* wr = w + (size_t)idx * HD;
    for (int k = tid; k < HD; k += 256)
      p += ((double)xh[k] + (double)xl[k]) * (double)wr[k];
    sd[tid] = p;
    __syncthreads();
    for (int off = 128; off; off >>= 1) {
      if (tid < off) sd[tid] += sd[tid + off];
      __syncthreads();
    }
    if (tid == 0) sd[0] += (double)ob[idx];
    __syncthreads();
    double tot = sd[0];
    if (tot > best || (tot == best && idx < bi)) { best = tot; bi = idx; }
    __syncthreads();
  }
  if (tid == 0) tok[b] = bi;
}

// ================= final log_softmax: out[b][t][v] -= lse[t][b], one big pass ======
__global__ void sub_all_k(float* __restrict__ out, const float* __restrict__ lse_all) {
  const long total = (long)NBATCH * TSTEPS * (VOC / 4);   // 40,960,000 float4
  long i = (long)blockIdx.x * 256 + threadIdx.x;
  const long stride = (long)gridDim.x * 256;
  for (; i < total; i += stride) {
    long b = i / (TSTEPS * (VOC / 4));
    long r = i - b * (TSTEPS * (VOC / 4));
    long t = r / (VOC / 4);
    float l = lse_all[t * NBATCH + b];
    float4 v = ((float4*)out)[i];
    v.x -= l; v.y -= l; v.z -= l; v.w -= l;
    ((float4*)out)[i] = v;
  }
}

// ================= final h output: out = hi + lo =================
__global__ void combine_h_k(const f16* __restrict__ hi, const f16* __restrict__ lo,
                            float* __restrict__ o, int n4) {
  int i = blockIdx.x * 256 + threadIdx.x;
  if (i >= n4) return;
  f16x4 h = ((const f16x4*)hi)[i];
  f16x4 l = ((const f16x4*)lo)[i];
  float4 v;
  v.x = (float)h[0] + (float)l[0];
  v.y = (float)h[1] + (float)l[1];
  v.z = (float)h[2] + (float)l[2];
  v.w = (float)h[3] + (float)l[3];
  ((float4*)o)[i] = v;
}

extern "C" void kernel_launch(void* const* d_in, const int* in_sizes, int n_in,
                              void* d_out, int out_size, void* d_ws, size_t ws_size,
                              hipStream_t stream) {
  (void)in_sizes; (void)n_in; (void)out_size;
  const float* enc_hidden = (const float*)d_in[1];   // [4,256,1024]
  const float* emb   = (const float*)d_in[2];        // [32000,1024]
  const float* w_ih  = (const float*)d_in[3];        // [4,3072,1024]
  const float* w_hh  = (const float*)d_in[4];        // [4,3072,1024]
  const float* b_ih  = (const float*)d_in[5];        // [4,3072]
  const float* b_hh  = (const float*)d_in[6];        // [4,3072]
  const float* out_w = (const float*)d_in[7];        // [32000,1024]
  const float* out_b = (const float*)d_in[8];        // [32000]
  float* out = (float*)d_out;

  size_t off = 0;
  char* base = (char*)d_ws;
  #define WSALLOC(bytes) ((void*)(base + off)); off += (((size_t)(bytes)) + 255) & ~(size_t)255
  float* gg2     = (float*) WSALLOC((size_t)2 * NBATCH * 6144 * 4);  // 12.6 MB
  f16*   hs_hi   = (f16*)   WSALLOC(2 * 4 * BH * 2);                 // 4.2 MB
  f16*   hs_lo   = (f16*)   WSALLOC(2 * 4 * BH * 2);                 // 4.2 MB
  int*   tok     = (int*)   WSALLOC(1024);
  float* pmax    = (float*) WSALLOC((size_t)NBATCH * NCHUNK * 4);    // 512 KB
  float* psum    = (float*) WSALLOC((size_t)NBATCH * NCHUNK * 4);    // 512 KB
  float* lse_all = (float*) WSALLOC((size_t)TSTEPS * NBATCH * 4);    // 20 KB
  f16*   wf16    = (f16*)   WSALLOC((size_t)VOC * HD * 2);           // 65.5 MB
  #undef WSALLOC
  if (off > ws_size) return;   // fail loudly rather than corrupt

  // one-time conversions
  f32_to_f16_k<<<2048, 256, 0, stream>>>(out_w, wf16, (long)VOC * HD / 8);
  split_f32_k<<<512, 256, 0, stream>>>(enc_hidden, hs_hi, hs_lo, (long)(4 * BH / 8));
  hipMemsetAsync(tok, 0, NBATCH * 4, stream);

  int p = 0;
  for (int t = 0; t < TSTEPS; ++t) {
    f16* hp_hi = hs_hi + (size_t)p * 4 * BH;
    f16* hp_lo = hs_lo + (size_t)p * 4 * BH;
    f16* hn_hi = hs_hi + (size_t)(1 - p) * 4 * BH;
    f16* hn_lo = hs_lo + (size_t)(1 - p) * 4 * BH;

    for (int l = 0; l < 4; ++l) {
      const f16* a0hi = (l == 0) ? hs_hi : hn_hi + (size_t)(l - 1) * BH;
      const f16* a0lo = (l == 0) ? hs_lo : hn_lo + (size_t)(l - 1) * BH;
      gemm_gru_mfma4_k<<<dim3(96, 4, 2), 256, 0, stream>>>(
          a0hi, a0lo, hp_hi + (size_t)l * BH, hp_lo + (size_t)l * BH,
          emb, tok, (l == 0) ? 1 : 0,
          w_ih + (size_t)l * 3072 * HD, w_hh + (size_t)l * 3072 * HD, gg2);
      gru_gates_split2_k<<<256, 256, 0, stream>>>(
          gg2, b_ih + l * 3072, b_hh + l * 3072,
          hp_hi + (size_t)l * BH, hp_lo + (size_t)l * BH,
          hn_hi + (size_t)l * BH, hn_lo + (size_t)l * BH);
    }

    float* lg = out + (size_t)t * VOC;   // raw logits land in d_out (strided)
    gemm_logits3_k<<<NCHUNK, 256, 0, stream>>>(
        hn_hi + (size_t)3 * BH, wf16, out_b, lg, pmax, psum);
    token_k<<<NBATCH, 256, 0, stream>>>(
        pmax, psum, lg, hn_hi + (size_t)3 * BH, hn_lo + (size_t)3 * BH,
        out_w, out_b, lse_all + (size_t)t * NBATCH, tok);

    p ^= 1;
  }

  // one full-bandwidth pass: log_probs = logits - lse
  sub_all_k<<<16384, 256, 0, stream>>>(out, lse_all);

  // after 20 steps the final h splits sit in parity 0
  combine_h_k<<<1024, 256, 0, stream>>>(hs_hi, hs_lo,
                                        out + (size_t)NBATCH * TSTEPS * VOC,
                                        (int)(4 * BH / 4));
}